// Round 8
// baseline (1238.394 us; speedup 1.0000x reference)
//
#include <hip/hip_runtime.h>
#include <hip/hip_fp16.h>

#define B_ 64
#define T_ 512
#define I_ 128
#define H_ 512

typedef _Float16 half2v __attribute__((ext_vector_type(2)));
typedef _Float16 f16x8  __attribute__((ext_vector_type(8)));
typedef float    f32x4  __attribute__((ext_vector_type(4)));

__device__ __forceinline__ float dot2(unsigned a, unsigned b, float c) {
    return __builtin_amdgcn_fdot2(__builtin_bit_cast(half2v, a),
                                  __builtin_bit_cast(half2v, b), c, false);
}

__device__ __forceinline__ unsigned short f32_to_f16b(float f) {
    _Float16 h = (_Float16)f;
    return __builtin_bit_cast(unsigned short, h);
}

// Builtin MFMA: compiler handles ALL hazard wait-states and operand classes
// (B operand is av-class: reads pinned AGPRs directly, no moves).
#define MFMA(ACC, A, Bq) \
    ACC = __builtin_amdgcn_mfma_f32_16x16x32_f16((A), (Bq), (ACC), 0, 0, 0)
#define BC(u) __builtin_bit_cast(f16x8, u)

// ---------------------------------------------------------------------------
// Kernel 1: W_hid fp32 [H,H] -> f16 MFMA B-fragments.  (unchanged)
// Fragment (w, kt, nt): lane l, elem j holds
//   B[k][n] = W_hid[n][k],  n = 64w + 16nt + (l&15),  k = 32kt + 8*(l>>4) + j
// stored at uint4 index ((w*16 + kt)*4 + nt)*64 + l  (dword m holds j=2m,2m+1).
// ---------------------------------------------------------------------------
__global__ void wconv(const float* __restrict__ Whid,
                      unsigned* __restrict__ Wz) {
    int p = blockIdx.x * 256 + threadIdx.x;   // dword index, 0..131071
    int m  = p & 3;
    int u4 = p >> 2;
    int l  = u4 & 63;
    int nt = (u4 >> 6) & 3;
    int kt = (u4 >> 8) & 15;
    int w  = (u4 >> 12) & 7;
    int h  = 64 * w + 16 * nt + (l & 15);     // n (output col) = h row of W_hid
    int k  = 32 * kt + 8 * (l >> 4) + 2 * m;
    float w0 = Whid[h * H_ + k];
    float w1 = Whid[h * H_ + k + 1];
    half2v hw = { (_Float16)w0, (_Float16)w1 };
    Wz[p] = __builtin_bit_cast(unsigned, hw);
}

// ---------------------------------------------------------------------------
// Kernel 2: v_in[b,t,h] = x[b,t,:] @ W_in[h,:] + b_in[h]  (unchanged)
// ---------------------------------------------------------------------------
__global__ __launch_bounds__(256) void vin_gemm(const float* __restrict__ x,
                                                const float* __restrict__ Win,
                                                const float* __restrict__ bin,
                                                float* __restrict__ vin) {
    __shared__ __align__(16) unsigned xs[64 * 64];   // 16 KB
    __shared__ __align__(16) unsigned ws[64 * 64];   // 16 KB
    const int tid = threadIdx.x;
    const int m0 = blockIdx.x * 64;
    const int n0 = blockIdx.y * 64;

    #pragma unroll
    for (int r = 0; r < 8; ++r) {
        int gi = r * 256 + tid;       // 0..2047
        int row = gi >> 5;            // 0..63
        int c4 = gi & 31;             // float4 index in the 128-float row
        float4 vx = ((const float4*)(x + (size_t)(m0 + row) * I_))[c4];
        float4 vw = ((const float4*)(Win + (size_t)(n0 + row) * I_))[c4];
        int sw = (row >> 2) & 15;
        int col = 4 * ((c4 >> 1) ^ sw) + (c4 & 1) * 2;  // swizzled dword col
        half2v x01 = { (_Float16)vx.x, (_Float16)vx.y };
        half2v x23 = { (_Float16)vx.z, (_Float16)vx.w };
        half2v w01 = { (_Float16)vw.x, (_Float16)vw.y };
        half2v w23 = { (_Float16)vw.z, (_Float16)vw.w };
        xs[row * 64 + col]     = __builtin_bit_cast(unsigned, x01);
        xs[row * 64 + col + 1] = __builtin_bit_cast(unsigned, x23);
        ws[row * 64 + col]     = __builtin_bit_cast(unsigned, w01);
        ws[row * 64 + col + 1] = __builtin_bit_cast(unsigned, w23);
    }
    __syncthreads();

    const int ty = tid >> 4, tx = tid & 15;
    float acc[4][4] = {};
    #pragma unroll
    for (int kb = 0; kb < 16; ++kb) {
        uint4 a4[4], b4[4];
        #pragma unroll
        for (int i = 0; i < 4; ++i)
            a4[i] = *(const uint4*)&xs[(ty * 4 + i) * 64 + 4 * (kb ^ ty)];
        #pragma unroll
        for (int j = 0; j < 4; ++j)
            b4[j] = *(const uint4*)&ws[(tx * 4 + j) * 64 + 4 * (kb ^ tx)];
        #pragma unroll
        for (int i = 0; i < 4; ++i)
            #pragma unroll
            for (int j = 0; j < 4; ++j) {
                acc[i][j] = dot2(a4[i].x, b4[j].x, acc[i][j]);
                acc[i][j] = dot2(a4[i].y, b4[j].y, acc[i][j]);
                acc[i][j] = dot2(a4[i].z, b4[j].z, acc[i][j]);
                acc[i][j] = dot2(a4[i].w, b4[j].w, acc[i][j]);
            }
    }

    float4 bv = ((const float4*)(bin + n0))[tx];
    #pragma unroll
    for (int i = 0; i < 4; ++i) {
        int m = m0 + ty * 4 + i;
        float4 o;
        o.x = acc[i][0] + bv.x; o.y = acc[i][1] + bv.y;
        o.z = acc[i][2] + bv.z; o.w = acc[i][3] + bv.w;
        ((float4*)(vin + (size_t)m * H_ + n0))[tx] = o;
    }
}

// ---------------------------------------------------------------------------
// Kernel 3: recurrence via MFMA.  R7 structure; pipe rebalance this round:
// B-fragment split now {kt 0..9 AGPR, kt 10..11 LDS, kt 12..15 L2}.
// The 4 L2 k-tiles use a 2-set rolling register stage (32 staging regs --
// identical envelope to R7's 8 held uint4s): issue kt12/13 at loop top,
// consume kt12 -> reissue set A as kt14, LDS kt10, consume kt13 -> reissue
// set B as kt15, LDS kt11, consume kt14, kt15.  LDS B-reads/thread 16 -> 8;
// W stays L2-resident (8 blocks/XCD share 512 KB in 4 MB XCD-L2).
// ---------------------------------------------------------------------------
__global__ __launch_bounds__(512, 2)
__attribute__((amdgpu_waves_per_eu(2, 2)))
void recurrent(
        const uint4* __restrict__ Wz4,
        const float* __restrict__ vin,
        const float* __restrict__ init_state,
        const float* __restrict__ b_hid,
        const float* __restrict__ alpha,
        float* __restrict__ out0,
        float* __restrict__ out1) {
    __shared__ uint4 ldsWb[4096];              // 64 KB : B-frags kt 10,11
    __shared__ unsigned short fr16[2][512];    //  2 KB : fr f16, dbuf

    const int t = threadIdx.x;
    const int b = blockIdx.x;
    const int w = t >> 6, l = t & 63;
    const int hi = l >> 4;                     // A k-group of this lane

    const uint4* wbase = Wz4 + (size_t)w * 4096 + l;

    // ---- park B-frags kt 0..9 in AGPRs (40 x 16B = 160 AGPRs) ------------
    f16x8 wb[10][4];
    #pragma unroll
    for (int kt = 0; kt < 10; ++kt)
        #pragma unroll
        for (int nt = 0; nt < 4; ++nt) {
            uint4 u = wbase[(kt * 4 + nt) * 64];
            wb[kt][nt] = __builtin_bit_cast(f16x8, u);
            asm("" : "+a"(wb[kt][nt]));        // force AGPR class at def
        }

    // ---- stage kt 10,11 into LDS: 8 uint4 per thread, coalesced ----------
    #pragma unroll
    for (int i = 0; i < 8; ++i)
        ldsWb[w * 512 + i * 64 + l] = wbase[2560 + i * 64];

    // ---- per-step L2-resident frags kt 12..15 (laundered base) -----------
    const uint4* gp = wbase;

    // ---- init ------------------------------------------------------------
    float v = init_state[b * H_ + t];
    fr16[0][t] = f32_to_f16b(fmaxf(v, 0.0f));
    const float bh = b_hid[t];
    const float al = alpha[t];
    const float om = 1.0f - al;
    const bool sel4 = (l & 16) != 0;
    const bool sel5 = (l & 32) != 0;

    const float* vinp = vin + (size_t)b * T_ * H_ + t;
    float* o0 = out0 + (size_t)b * T_ * H_ + t;
    float* o1 = out1 + (size_t)b * T_ * H_ + t;

    __syncthreads();

    for (int s = 0; s < T_; ++s) {
        const int par = s & 1;

        // launder so loads re-issue per step (L2-hot) instead of pinning regs
        asm volatile("" : "+v"(gp));
        // issue kt12 (set A) and kt13 (set B)
        uint4 gA0 = gp[3072], gA1 = gp[3136], gA2 = gp[3200], gA3 = gp[3264];
        uint4 gB0 = gp[3328], gB1 = gp[3392], gB2 = gp[3456], gB3 = gp[3520];
        float vinv = vinp[(size_t)s * H_];     // early issue, used late

        f32x4 acc0 = {0.f, 0.f, 0.f, 0.f}, acc1 = {0.f, 0.f, 0.f, 0.f};
        f32x4 acc2 = {0.f, 0.f, 0.f, 0.f}, acc3 = {0.f, 0.f, 0.f, 0.f};

        // A-fragments: 16B broadcast per 16-lane group; rows replicated = fr
        const f16x8* frb =
            (const f16x8*)((const char*)&fr16[par][0] + hi * 16);

        // ---- kt 0..9 from AGPR (no memory traffic) -----------------------
        #pragma unroll
        for (int kt = 0; kt < 10; ++kt) {
            f16x8 afr = frb[kt * 4];
            MFMA(acc0, afr, wb[kt][0]);
            MFMA(acc1, afr, wb[kt][1]);
            MFMA(acc2, afr, wb[kt][2]);
            MFMA(acc3, afr, wb[kt][3]);
        }
        // ---- kt12 from L2 (set A), then reissue set A as kt14 ------------
        {
            f16x8 a12 = frb[12 * 4];
            MFMA(acc0, a12, BC(gA0));
            MFMA(acc1, a12, BC(gA1));
            MFMA(acc2, a12, BC(gA2));
            MFMA(acc3, a12, BC(gA3));
        }
        gA0 = gp[3584]; gA1 = gp[3648]; gA2 = gp[3712]; gA3 = gp[3776];
        // ---- kt10 from LDS ----------------------------------------------
        {
            f16x8 a10 = frb[10 * 4];
            const f16x8* lb = (const f16x8*)&ldsWb[w * 512 + l];
            MFMA(acc0, a10, lb[0]);
            MFMA(acc1, a10, lb[64]);
            MFMA(acc2, a10, lb[128]);
            MFMA(acc3, a10, lb[192]);
        }
        // ---- kt13 from L2 (set B), then reissue set B as kt15 ------------
        {
            f16x8 a13 = frb[13 * 4];
            MFMA(acc0, a13, BC(gB0));
            MFMA(acc1, a13, BC(gB1));
            MFMA(acc2, a13, BC(gB2));
            MFMA(acc3, a13, BC(gB3));
        }
        gB0 = gp[3840]; gB1 = gp[3904]; gB2 = gp[3968]; gB3 = gp[4032];
        // ---- kt11 from LDS ----------------------------------------------
        {
            f16x8 a11 = frb[11 * 4];
            const f16x8* lb = (const f16x8*)&ldsWb[w * 512 + 256 + l];
            MFMA(acc0, a11, lb[0]);
            MFMA(acc1, a11, lb[64]);
            MFMA(acc2, a11, lb[128]);
            MFMA(acc3, a11, lb[192]);
        }
        // ---- kt14 (set A), kt15 (set B) from L2 --------------------------
        {
            f16x8 a14 = frb[14 * 4];
            MFMA(acc0, a14, BC(gA0));
            MFMA(acc1, a14, BC(gA1));
            MFMA(acc2, a14, BC(gA2));
            MFMA(acc3, a14, BC(gA3));
            f16x8 a15 = frb[15 * 4];
            MFMA(acc0, a15, BC(gB0));
            MFMA(acc1, a15, BC(gB1));
            MFMA(acc2, a15, BC(gB2));
            MFMA(acc3, a15, BC(gB3));
        }

        // lane l holds result for h = 64w + 16*nt + (l&15); pick nt
        float s01 = sel4 ? acc1.x : acc0.x;
        float s23 = sel4 ? acc3.x : acc2.x;
        float vh  = sel5 ? s23 : s01;

        float vhid = vh + bh;
        float vnew = om * v + al * (vhid + vinv);
        float frn  = fmaxf(vnew, 0.0f);
        fr16[par ^ 1][t] = f32_to_f16b(frn);   // fr first: barrier gates this
        float vr = om * vnew + al * vhid;
        v = vnew;
        float frr = fmaxf(vr, 0.0f);
        o0[(size_t)s * H_] = frn;              // fire-and-forget
        o1[(size_t)s * H_] = frr;

        // fr visible to all waves; no vmcnt drain in the loop
        asm volatile("s_waitcnt lgkmcnt(0)" ::: "memory");
        __builtin_amdgcn_s_barrier();
    }
}

// ---------------------------------------------------------------------------
extern "C" void kernel_launch(void* const* d_in, const int* in_sizes, int n_in,
                              void* d_out, int out_size, void* d_ws, size_t ws_size,
                              hipStream_t stream) {
    const float* x          = (const float*)d_in[0];
    const float* init_state = (const float*)d_in[1];
    const float* W_in       = (const float*)d_in[2];
    const float* b_in       = (const float*)d_in[3];
    const float* W_hid      = (const float*)d_in[4];
    const float* b_hid      = (const float*)d_in[5];
    const float* alpha      = (const float*)d_in[6];

    float* out0 = (float*)d_out;
    float* out1 = out0 + (size_t)B_ * T_ * H_;

    char* ws = (char*)d_ws;
    float*    vin = (float*)ws;                    // 67,108,864 B
    unsigned* Wz  = (unsigned*)(ws + 67108864);    //    524,288 B

    hipLaunchKernelGGL(wconv, dim3(512), dim3(256), 0, stream,
                       W_hid, Wz);
    hipLaunchKernelGGL(vin_gemm, dim3(512, 8), dim3(256), 0, stream,
                       x, W_in, b_in, vin);
    hipLaunchKernelGGL(recurrent, dim3(64), dim3(512), 0, stream,
                       (const uint4*)Wz, vin, init_state, b_hid, alpha,
                       out0, out1);
}

// Round 9
// 840.291 us; speedup vs baseline: 1.4738x; 1.4738x over previous
//
#include <hip/hip_runtime.h>
#include <hip/hip_fp16.h>

#define B_ 64
#define T_ 512
#define I_ 128
#define H_ 512

typedef _Float16 half2v __attribute__((ext_vector_type(2)));
typedef _Float16 f16x8  __attribute__((ext_vector_type(8)));
typedef float    f32x4  __attribute__((ext_vector_type(4)));

__device__ __forceinline__ float dot2(unsigned a, unsigned b, float c) {
    return __builtin_amdgcn_fdot2(__builtin_bit_cast(half2v, a),
                                  __builtin_bit_cast(half2v, b), c, false);
}

__device__ __forceinline__ unsigned short f32_to_f16b(float f) {
    _Float16 h = (_Float16)f;
    return __builtin_bit_cast(unsigned short, h);
}

// Builtin MFMA: compiler handles ALL hazard wait-states and operand classes
// (B operand is av-class: reads pinned AGPRs directly, no moves).
#define MFMA(ACC, A, Bq) \
    ACC = __builtin_amdgcn_mfma_f32_16x16x32_f16((A), (Bq), (ACC), 0, 0, 0)
#define BC(u) __builtin_bit_cast(f16x8, u)

// ---------------------------------------------------------------------------
// Kernel 1: W_hid fp32 [H,H] -> f16 MFMA B-fragments.  (unchanged)
// Fragment (w, kt, nt): lane l, elem j holds
//   B[k][n] = W_hid[n][k],  n = 64w + 16nt + (l&15),  k = 32kt + 8*(l>>4) + j
// stored at uint4 index ((w*16 + kt)*4 + nt)*64 + l  (dword m holds j=2m,2m+1).
// ---------------------------------------------------------------------------
__global__ void wconv(const float* __restrict__ Whid,
                      unsigned* __restrict__ Wz) {
    int p = blockIdx.x * 256 + threadIdx.x;   // dword index, 0..131071
    int m  = p & 3;
    int u4 = p >> 2;
    int l  = u4 & 63;
    int nt = (u4 >> 6) & 3;
    int kt = (u4 >> 8) & 15;
    int w  = (u4 >> 12) & 7;
    int h  = 64 * w + 16 * nt + (l & 15);     // n (output col) = h row of W_hid
    int k  = 32 * kt + 8 * (l >> 4) + 2 * m;
    float w0 = Whid[h * H_ + k];
    float w1 = Whid[h * H_ + k + 1];
    half2v hw = { (_Float16)w0, (_Float16)w1 };
    Wz[p] = __builtin_bit_cast(unsigned, hw);
}

// ---------------------------------------------------------------------------
// Kernel 2: v_in[b,t,h] = x[b,t,:] @ W_in[h,:] + b_in[h]  (unchanged)
// ---------------------------------------------------------------------------
__global__ __launch_bounds__(256) void vin_gemm(const float* __restrict__ x,
                                                const float* __restrict__ Win,
                                                const float* __restrict__ bin,
                                                float* __restrict__ vin) {
    __shared__ __align__(16) unsigned xs[64 * 64];   // 16 KB
    __shared__ __align__(16) unsigned ws[64 * 64];   // 16 KB
    const int tid = threadIdx.x;
    const int m0 = blockIdx.x * 64;
    const int n0 = blockIdx.y * 64;

    #pragma unroll
    for (int r = 0; r < 8; ++r) {
        int gi = r * 256 + tid;       // 0..2047
        int row = gi >> 5;            // 0..63
        int c4 = gi & 31;             // float4 index in the 128-float row
        float4 vx = ((const float4*)(x + (size_t)(m0 + row) * I_))[c4];
        float4 vw = ((const float4*)(Win + (size_t)(n0 + row) * I_))[c4];
        int sw = (row >> 2) & 15;
        int col = 4 * ((c4 >> 1) ^ sw) + (c4 & 1) * 2;  // swizzled dword col
        half2v x01 = { (_Float16)vx.x, (_Float16)vx.y };
        half2v x23 = { (_Float16)vx.z, (_Float16)vx.w };
        half2v w01 = { (_Float16)vw.x, (_Float16)vw.y };
        half2v w23 = { (_Float16)vw.z, (_Float16)vw.w };
        xs[row * 64 + col]     = __builtin_bit_cast(unsigned, x01);
        xs[row * 64 + col + 1] = __builtin_bit_cast(unsigned, x23);
        ws[row * 64 + col]     = __builtin_bit_cast(unsigned, w01);
        ws[row * 64 + col + 1] = __builtin_bit_cast(unsigned, w23);
    }
    __syncthreads();

    const int ty = tid >> 4, tx = tid & 15;
    float acc[4][4] = {};
    #pragma unroll
    for (int kb = 0; kb < 16; ++kb) {
        uint4 a4[4], b4[4];
        #pragma unroll
        for (int i = 0; i < 4; ++i)
            a4[i] = *(const uint4*)&xs[(ty * 4 + i) * 64 + 4 * (kb ^ ty)];
        #pragma unroll
        for (int j = 0; j < 4; ++j)
            b4[j] = *(const uint4*)&ws[(tx * 4 + j) * 64 + 4 * (kb ^ tx)];
        #pragma unroll
        for (int i = 0; i < 4; ++i)
            #pragma unroll
            for (int j = 0; j < 4; ++j) {
                acc[i][j] = dot2(a4[i].x, b4[j].x, acc[i][j]);
                acc[i][j] = dot2(a4[i].y, b4[j].y, acc[i][j]);
                acc[i][j] = dot2(a4[i].z, b4[j].z, acc[i][j]);
                acc[i][j] = dot2(a4[i].w, b4[j].w, acc[i][j]);
            }
    }

    float4 bv = ((const float4*)(bin + n0))[tx];
    #pragma unroll
    for (int i = 0; i < 4; ++i) {
        int m = m0 + ty * 4 + i;
        float4 o;
        o.x = acc[i][0] + bv.x; o.y = acc[i][1] + bv.y;
        o.z = acc[i][2] + bv.z; o.w = acc[i][3] + bv.w;
        ((float4*)(vin + (size_t)m * H_ + n0))[tx] = o;
    }
}

// ---------------------------------------------------------------------------
// Kernel 3: recurrence via MFMA.  This round: ZERO per-step W memory traffic
// from L2 -- B-fragment split {kt 0..9 AGPR-parked, kt 10..13 LDS (128 KB),
// kt 14..15 held in 32 VGPRs (loop-invariant, loaded once)}.  Plus vinv
// software pipeline: next step's vin element loaded a FULL step ahead, so
// its HBM latency (~900 cyc) is no longer on the per-step critical path.
// One lgkm-only barrier per step; stores fire-and-forget (vmcnt never
// drained in the loop).
// ---------------------------------------------------------------------------
__global__ __launch_bounds__(512, 2)
__attribute__((amdgpu_waves_per_eu(2, 2)))
void recurrent(
        const uint4* __restrict__ Wz4,
        const float* __restrict__ vin,
        const float* __restrict__ init_state,
        const float* __restrict__ b_hid,
        const float* __restrict__ alpha,
        float* __restrict__ out0,
        float* __restrict__ out1) {
    __shared__ uint4 ldsWb[8192];              // 128 KB : B-frags kt 10..13
    __shared__ unsigned short fr16[2][512];    //   2 KB : fr f16, dbuf

    const int t = threadIdx.x;
    const int b = blockIdx.x;
    const int w = t >> 6, l = t & 63;
    const int hi = l >> 4;                     // A k-group of this lane

    const uint4* wbase = Wz4 + (size_t)w * 4096 + l;

    // ---- park B-frags kt 0..9 in AGPRs (40 x 16B = 160 AGPRs) ------------
    f16x8 wb[10][4];
    #pragma unroll
    for (int kt = 0; kt < 10; ++kt)
        #pragma unroll
        for (int nt = 0; nt < 4; ++nt) {
            uint4 u = wbase[(kt * 4 + nt) * 64];
            wb[kt][nt] = __builtin_bit_cast(f16x8, u);
            asm("" : "+a"(wb[kt][nt]));        // force AGPR class at def
        }

    // ---- stage kt 10..13 into LDS: 16 uint4 per thread, coalesced --------
    #pragma unroll
    for (int i = 0; i < 16; ++i)
        ldsWb[w * 1024 + i * 64 + l] = wbase[2560 + i * 64];

    // ---- kt 14..15 held in VGPRs (loop-invariant, 32 regs) ---------------
    uint4 h14_0 = wbase[3584], h14_1 = wbase[3648];
    uint4 h14_2 = wbase[3712], h14_3 = wbase[3776];
    uint4 h15_0 = wbase[3840], h15_1 = wbase[3904];
    uint4 h15_2 = wbase[3968], h15_3 = wbase[4032];

    // ---- init ------------------------------------------------------------
    float v = init_state[b * H_ + t];
    fr16[0][t] = f32_to_f16b(fmaxf(v, 0.0f));
    const float bh = b_hid[t];
    const float al = alpha[t];
    const float om = 1.0f - al;
    const bool sel4 = (l & 16) != 0;
    const bool sel5 = (l & 32) != 0;

    const float* vinp = vin + (size_t)b * T_ * H_ + t;
    float* o0 = out0 + (size_t)b * T_ * H_ + t;
    float* o1 = out1 + (size_t)b * T_ * H_ + t;

    float vinv = vinp[0];                      // step-0 element, pre-loaded

    __syncthreads();

    for (int s = 0; s < T_; ++s) {
        const int par = s & 1;

        // prefetch NEXT step's vin element: a full step of latency cover
        int sn = (s + 1) & (T_ - 1);           // in-bounds; last one unused
        float vinv_next = vinp[(size_t)sn * H_];

        f32x4 acc0 = {0.f, 0.f, 0.f, 0.f}, acc1 = {0.f, 0.f, 0.f, 0.f};
        f32x4 acc2 = {0.f, 0.f, 0.f, 0.f}, acc3 = {0.f, 0.f, 0.f, 0.f};

        // A-fragments: 16B broadcast per 16-lane group; rows replicated = fr
        const f16x8* frb =
            (const f16x8*)((const char*)&fr16[par][0] + hi * 16);

        // ---- kt 0..9 from AGPR (no memory traffic) -----------------------
        #pragma unroll
        for (int kt = 0; kt < 10; ++kt) {
            f16x8 afr = frb[kt * 4];
            MFMA(acc0, afr, wb[kt][0]);
            MFMA(acc1, afr, wb[kt][1]);
            MFMA(acc2, afr, wb[kt][2]);
            MFMA(acc3, afr, wb[kt][3]);
        }
        // ---- kt 10..13 from LDS ------------------------------------------
        #pragma unroll
        for (int kt = 10; kt < 14; ++kt) {
            f16x8 afr = frb[kt * 4];
            const f16x8* lb =
                (const f16x8*)&ldsWb[w * 1024 + (kt - 10) * 256 + l];
            MFMA(acc0, afr, lb[0]);
            MFMA(acc1, afr, lb[64]);
            MFMA(acc2, afr, lb[128]);
            MFMA(acc3, afr, lb[192]);
        }
        // ---- kt 14..15 from held VGPRs (no memory traffic) ---------------
        {
            f16x8 a14 = frb[14 * 4];
            MFMA(acc0, a14, BC(h14_0));
            MFMA(acc1, a14, BC(h14_1));
            MFMA(acc2, a14, BC(h14_2));
            MFMA(acc3, a14, BC(h14_3));
            f16x8 a15 = frb[15 * 4];
            MFMA(acc0, a15, BC(h15_0));
            MFMA(acc1, a15, BC(h15_1));
            MFMA(acc2, a15, BC(h15_2));
            MFMA(acc3, a15, BC(h15_3));
        }

        // lane l holds result for h = 64w + 16*nt + (l&15); pick nt
        float s01 = sel4 ? acc1.x : acc0.x;
        float s23 = sel4 ? acc3.x : acc2.x;
        float vh  = sel5 ? s23 : s01;

        float vhid = vh + bh;
        float vnew = om * v + al * (vhid + vinv);
        float frn  = fmaxf(vnew, 0.0f);
        fr16[par ^ 1][t] = f32_to_f16b(frn);   // fr first: barrier gates this
        float vr = om * vnew + al * vhid;
        v = vnew;
        vinv = vinv_next;                      // consume prefetched element
        float frr = fmaxf(vr, 0.0f);
        o0[(size_t)s * H_] = frn;              // fire-and-forget
        o1[(size_t)s * H_] = frr;

        // fr visible to all waves; no vmcnt drain in the loop
        asm volatile("s_waitcnt lgkmcnt(0)" ::: "memory");
        __builtin_amdgcn_s_barrier();
    }
}

// ---------------------------------------------------------------------------
extern "C" void kernel_launch(void* const* d_in, const int* in_sizes, int n_in,
                              void* d_out, int out_size, void* d_ws, size_t ws_size,
                              hipStream_t stream) {
    const float* x          = (const float*)d_in[0];
    const float* init_state = (const float*)d_in[1];
    const float* W_in       = (const float*)d_in[2];
    const float* b_in       = (const float*)d_in[3];
    const float* W_hid      = (const float*)d_in[4];
    const float* b_hid      = (const float*)d_in[5];
    const float* alpha      = (const float*)d_in[6];

    float* out0 = (float*)d_out;
    float* out1 = out0 + (size_t)B_ * T_ * H_;

    char* ws = (char*)d_ws;
    float*    vin = (float*)ws;                    // 67,108,864 B
    unsigned* Wz  = (unsigned*)(ws + 67108864);    //    524,288 B

    hipLaunchKernelGGL(wconv, dim3(512), dim3(256), 0, stream,
                       W_hid, Wz);
    hipLaunchKernelGGL(vin_gemm, dim3(512, 8), dim3(256), 0, stream,
                       x, W_in, b_in, vin);
    hipLaunchKernelGGL(recurrent, dim3(64), dim3(512), 0, stream,
                       (const uint4*)Wz, vin, init_state, b_hid, alpha,
                       out0, out1);
}